// Round 1
// 2549.558 us; speedup vs baseline: 1.4114x; 1.4114x over previous
//
#include <hip/hip_runtime.h>

// ---------- constants ----------
#define B_   64
#define P_   196
#define ENC_ 512
#define ATT_ 256
#define DEC_ 256
#define EMB_ 256
#define V_   10000
#define T_   44
#define G4_  1024          // 4*DEC
#define XW_  768           // EMB+ENC (W_ih inner dim)

using short8 = __attribute__((ext_vector_type(8))) short;
using f32x4  = __attribute__((ext_vector_type(4))) float;

__device__ __forceinline__ unsigned short f2bf(float f) {
    unsigned int u = __float_as_uint(f);
    unsigned int r = (u + 0x7fffu + ((u >> 16) & 1u)) >> 16;
    return (unsigned short)r;
}

// ---------- generic 32x32 transpose: dst[k*N + n] = src[n*stride + off + k] ----------
__global__ void k_transpose(const float* __restrict__ src, float* __restrict__ dst,
                            int N, int stride, int off) {
    __shared__ float t[32][33];
    int k0 = blockIdx.x * 32, n0 = blockIdx.y * 32;
    int tx = threadIdx.x & 31, ty = threadIdx.x >> 5;
    for (int r = ty; r < 32; r += 8)
        t[r][tx] = src[(size_t)(n0 + r) * stride + off + k0 + tx];
    __syncthreads();
    for (int r = ty; r < 32; r += 8)
        dst[(size_t)(k0 + r) * N + n0 + tx] = t[tx][r];
}

// ---------- pack gate weights: dst[(k*256+d)] = float4{ W[d][k], W[256+d][k], W[512+d][k], W[768+d][k] }
// src is [1024][stride] row-major (j = g*256+d), k < kmax (pow2). One thread per (d,k).
__global__ __launch_bounds__(256) void k_packW(const float* __restrict__ src,
        float* __restrict__ dst, int kmax, int logk, int stride) {
    int idx = blockIdx.x * 256 + threadIdx.x;
    int k = idx & (kmax - 1), d = idx >> logk;
    float4 v;
    v.x = src[(size_t)(d      ) * stride + k];
    v.y = src[(size_t)(d + 256) * stride + k];
    v.z = src[(size_t)(d + 512) * stride + k];
    v.w = src[(size_t)(d + 768) * stride + k];
    reinterpret_cast<float4*>(dst)[(size_t)k * 256 + d] = v;
}

// ---------- fp32 -> bf16 convert ----------
__global__ void k_cvt(const float* __restrict__ src, unsigned short* __restrict__ dst, int n) {
    int i = blockIdx.x * 256 + threadIdx.x;
    if (i < n) dst[i] = f2bf(src[i]);
}

// ---------- h0/c0 from mean-pooled encoder ----------
__global__ __launch_bounds__(256) void k_init_state(
        const float* __restrict__ enc,
        const float* __restrict__ W_init_h, const float* __restrict__ b_init_h,
        const float* __restrict__ W_init_c, const float* __restrict__ b_init_c,
        float* __restrict__ h0, float* __restrict__ c0) {
    int b = blockIdx.x, tid = threadIdx.x;
    __shared__ float avg[ENC_];
    for (int e = tid; e < ENC_; e += 256) {
        float s = 0.f;
        const float* p = enc + (size_t)b * P_ * ENC_ + e;
        for (int i = 0; i < P_; i++) s += p[(size_t)i * ENC_];
        avg[e] = s * (1.0f / (float)P_);
    }
    __syncthreads();
    int d = tid;  // 256 threads == DEC_
    float hs = b_init_h[d], cs = b_init_c[d];
    const float* wh = W_init_h + (size_t)d * ENC_;
    const float* wc = W_init_c + (size_t)d * ENC_;
    for (int e = 0; e < ENC_; e++) { float a = avg[e]; hs += a * wh[e]; cs += a * wc[e]; }
    h0[b * DEC_ + d] = hs;
    c0[b * DEC_ + d] = cs;
}

// ---------- att1T[b][a][p] = sum_e enc[b,p,e] * W_enc_att[a,e] ----------
// grid: 64 b * 4 a-tiles(64)
__global__ __launch_bounds__(256) void k_att1(
        const float* __restrict__ enc, const float* __restrict__ Wea,
        float* __restrict__ att1T) {
    int b = blockIdx.x >> 2, a0 = (blockIdx.x & 3) * 64;
    __shared__ float encT[32][257];   // [e_local][p] padded
    __shared__ float Wt[64][32];      // [a_local][e_local]
    int tid = threadIdx.x;
    int pl = tid & 63, ia = tid >> 6;
    float acc[16][4];
#pragma unroll
    for (int k = 0; k < 16; k++)
#pragma unroll
        for (int q = 0; q < 4; q++) acc[k][q] = 0.f;

    for (int e0 = 0; e0 < ENC_; e0 += 32) {
        {
            int j = tid & 31, pr = tid >> 5;
            for (int pass = 0; pass < 32; pass++) {
                int p = pr + pass * 8;
                float v = 0.f;
                if (p < P_) v = enc[((size_t)b * P_ + p) * ENC_ + e0 + j];
                encT[j][p] = v;
            }
            int r = tid >> 2, c0 = (tid & 3) * 8;
#pragma unroll
            for (int i = 0; i < 8; i++)
                Wt[r][c0 + i] = Wea[(size_t)(a0 + r) * ENC_ + e0 + c0 + i];
        }
        __syncthreads();
        for (int e = 0; e < 32; e++) {
            float e0v = encT[e][pl], e1v = encT[e][pl + 64];
            float e2v = encT[e][pl + 128], e3v = encT[e][pl + 192];
#pragma unroll
            for (int k = 0; k < 16; k++) {
                float w = Wt[ia * 16 + k][e];
                acc[k][0] += w * e0v; acc[k][1] += w * e1v;
                acc[k][2] += w * e2v; acc[k][3] += w * e3v;
            }
        }
        __syncthreads();
    }
#pragma unroll
    for (int k = 0; k < 16; k++)
#pragma unroll
        for (int q = 0; q < 4; q++) {
            int p = pl + 64 * q;
            if (p < P_)
                att1T[(size_t)b * (ATT_ * P_) + (size_t)(a0 + ia * 16 + k) * P_ + p] = acc[k][q];
        }
}

// ---------- embW[(t*64+b)][j] = b_ih[j]+b_hh[j] + sum_e emb[cap(b,t)][e]*W_ih[j][512+e] ----------
// grid: 2816/16 = 176 blocks
__global__ __launch_bounds__(256) void k_embW(
        const int* __restrict__ caption, const float* __restrict__ embedding,
        const float* __restrict__ WiheT, const float* __restrict__ b_ih,
        const float* __restrict__ b_hh, float* __restrict__ embW) {
    int r0 = blockIdx.x * 16, tid = threadIdx.x;
    __shared__ float embL[16][256];
    __shared__ int capL[16];
    if (tid < 16) {
        int r = r0 + tid, t = r >> 6, b = r & 63;
        capL[tid] = caption[b * T_ + t];
    }
    __syncthreads();
#pragma unroll
    for (int lr = 0; lr < 16; lr++)
        embL[lr][tid] = embedding[(size_t)capL[lr] * EMB_ + tid];
    __syncthreads();
    float base0 = b_ih[tid] + b_hh[tid];
    float base1 = b_ih[tid + 256] + b_hh[tid + 256];
    float base2 = b_ih[tid + 512] + b_hh[tid + 512];
    float base3 = b_ih[tid + 768] + b_hh[tid + 768];
    float acc[16][4];
#pragma unroll
    for (int lr = 0; lr < 16; lr++) {
        acc[lr][0] = base0; acc[lr][1] = base1; acc[lr][2] = base2; acc[lr][3] = base3;
    }
    for (int e = 0; e < EMB_; e++) {
        const float* wr = WiheT + (size_t)e * G4_ + tid;
        float w0 = wr[0], w1 = wr[256], w2 = wr[512], w3 = wr[768];
#pragma unroll
        for (int lr = 0; lr < 16; lr++) {
            float ev = embL[lr][e];
            acc[lr][0] += w0 * ev; acc[lr][1] += w1 * ev;
            acc[lr][2] += w2 * ev; acc[lr][3] += w3 * ev;
        }
    }
#pragma unroll
    for (int lr = 0; lr < 16; lr++) {
        float* o = embW + (size_t)(r0 + lr) * G4_ + tid;
        o[0] = acc[lr][0]; o[256] = acc[lr][1]; o[512] = acc[lr][2]; o[768] = acc[lr][3];
    }
}

// ---------- the sequential recurrence: one block (1024 thr = 16 waves) per batch element ----------
// Split-k on every phase so all 16 waves work; gate weights packed as [k][d][4] float4.
__global__ __launch_bounds__(1024) void k_recur(
        const float* __restrict__ enc, const float* __restrict__ att1T,
        const float* __restrict__ WdaT, const float* __restrict__ W_full,
        const float* __restrict__ WihcP, const float* __restrict__ WhhP,
        const float* __restrict__ embW, const float* __restrict__ h0,
        const float* __restrict__ c0,
        unsigned short* __restrict__ Hbf, float* __restrict__ out_alpha) {
    int b = blockIdx.x, tid = threadIdx.x;
    int q = tid >> 8;        // 0..3 : k-split group
    int r = tid & 255;       // 0..255
    __shared__ float h_l[DEC_], att2_l[ATT_], alpha_l[256], ctx_l[ENC_], wf_l[ATT_];
    __shared__ float red_l[8];
    __shared__ float p1[4][256];
    __shared__ float p2[4][256];
    __shared__ float p3[2][512];
    __shared__ __align__(16) float4 p4[4][256];

    if (tid < 256) {
        h_l[tid] = h0[b * DEC_ + tid];
        wf_l[tid] = W_full[tid];
    }
    float c = (tid < 256) ? c0[b * DEC_ + tid] : 0.f;
    __syncthreads();
    const float* att1b = att1T + (size_t)b * (ATT_ * P_);
    const float* encb  = enc   + (size_t)b * P_ * ENC_;
    const float4* Wc4 = reinterpret_cast<const float4*>(WihcP);
    const float4* Wh4 = reinterpret_cast<const float4*>(WhhP);

    for (int t = 0; t < T_; t++) {
        // P1: att2 = h @ W_dec_att^T, d split 4-way (r = a)
        {
            float a2 = 0.f;
            int d0 = q * 64;
#pragma unroll 8
            for (int d = d0; d < d0 + 64; d++)
                a2 += WdaT[d * ATT_ + r] * h_l[d];
            p1[q][r] = a2;
        }
        __syncthreads();
        if (tid < 256) att2_l[tid] = p1[0][tid] + p1[1][tid] + p1[2][tid] + p1[3][tid];
        __syncthreads();

        // P2: scores partials, a split 4-way (r = p)
        {
            float sp = 0.f;
            if (r < P_) {
                int a0 = q * 64;
#pragma unroll 4
                for (int a = a0; a < a0 + 64; a++) {
                    float v = att1b[(size_t)a * P_ + r] + att2_l[a];
                    sp += fmaxf(v, 0.f) * wf_l[a];
                }
            }
            p2[q][r] = sp;
        }
        __syncthreads();
        // softmax over p (done by tid<256; all threads hit the barriers)
        float s = -1e30f;
        if (tid < P_)
            s = p2[0][tid] + p2[1][tid] + p2[2][tid] + p2[3][tid];
        float m = s;
#pragma unroll
        for (int off = 32; off; off >>= 1) m = fmaxf(m, __shfl_xor(m, off));
        if (tid < 256 && (tid & 63) == 0) red_l[tid >> 6] = m;
        __syncthreads();
        m = fmaxf(fmaxf(red_l[0], red_l[1]), fmaxf(red_l[2], red_l[3]));
        float ex = (tid < P_) ? __expf(s - m) : 0.f;
        float sm = ex;
#pragma unroll
        for (int off = 32; off; off >>= 1) sm += __shfl_xor(sm, off);
        if (tid < 256 && (tid & 63) == 0) red_l[4 + (tid >> 6)] = sm;
        __syncthreads();
        sm = red_l[4] + red_l[5] + red_l[6] + red_l[7];
        if (tid < 256) {
            float alpha = ex / sm;
            alpha_l[tid] = alpha;
            if (tid < P_) out_alpha[(size_t)b * (T_ * P_) + t * P_ + tid] = alpha;
        }
        __syncthreads();

        // P3: ctx = alpha @ enc[b], p split 2-way (tid&511 = e)
        {
            int e = tid & 511, ph = tid >> 9;
            int pb = ph ? 98 : 0, pe = ph ? P_ : 98;
            float cx = 0.f;
#pragma unroll 2
            for (int p = pb; p < pe; p++)
                cx += alpha_l[p] * encb[(size_t)p * ENC_ + e];
            p3[ph][e] = cx;
        }
        __syncthreads();
        if (tid < 512) ctx_l[tid] = p3[0][tid] + p3[1][tid];
        __syncthreads();

        // P4: gates, k(768) split 4-way (192 per q), float4 packed weights [k][d][4gates]
        {
            float4 acc = {0.f, 0.f, 0.f, 0.f};
            int kb = q * 192, ke = kb + 192;
            int eb = (kb < ENC_) ? kb : ENC_;
            int ee = (ke < ENC_) ? ke : ENC_;
#pragma unroll 4
            for (int e = eb; e < ee; e++) {
                float4 w = Wc4[(size_t)e * 256 + r];
                float xv = ctx_l[e];
                acc.x += w.x * xv; acc.y += w.y * xv;
                acc.z += w.z * xv; acc.w += w.w * xv;
            }
            int hb = (kb > ENC_) ? kb - ENC_ : 0;
            int he = (ke > ENC_) ? ke - ENC_ : 0;
#pragma unroll 4
            for (int d = hb; d < he; d++) {
                float4 w = Wh4[(size_t)d * 256 + r];
                float xv = h_l[d];
                acc.x += w.x * xv; acc.y += w.y * xv;
                acc.z += w.z * xv; acc.w += w.w * xv;
            }
            p4[q][r] = acc;
        }
        __syncthreads();

        // P5: reduce gate partials + LSTM pointwise (torch gate order i,f,g,o)
        if (tid < 256) {
            float4 g0v = p4[0][tid], g1v = p4[1][tid], g2v = p4[2][tid], g3v = p4[3][tid];
            const float* ew = embW + ((size_t)t * B_ + b) * G4_;
            float gi = g0v.x + g1v.x + g2v.x + g3v.x + ew[tid];
            float gf = g0v.y + g1v.y + g2v.y + g3v.y + ew[tid + 256];
            float gg = g0v.z + g1v.z + g2v.z + g3v.z + ew[tid + 512];
            float go = g0v.w + g1v.w + g2v.w + g3v.w + ew[tid + 768];
            float i_g = 1.f / (1.f + __expf(-gi));
            float f_g = 1.f / (1.f + __expf(-gf));
            float g_g = tanhf(gg);
            float o_g = 1.f / (1.f + __expf(-go));
            c = f_g * c + i_g * g_g;
            float hn = o_g * tanhf(c);
            h_l[tid] = hn;
            Hbf[((size_t)t * B_ + b) * DEC_ + tid] = f2bf(hn);
        }
        __syncthreads();
    }
}

// ---------- logits: C[m][n] = H[m,:] . Wout[n,:] + b_out[n], bf16 MFMA ----------
// m = t*64+b, out[b*T*V + t*V + n]. grid: (79 n-tiles, 22 m-tiles), 256 thr.
__global__ __launch_bounds__(256) void k_logits(
        const unsigned short* __restrict__ Hbf, const unsigned short* __restrict__ Woutbf,
        const float* __restrict__ b_out, float* __restrict__ out) {
    int n0 = blockIdx.x * 128, m0 = blockIdx.y * 128;
    __shared__ __align__(16) unsigned short At[128][40];
    __shared__ __align__(16) unsigned short Bt[128][40];
    int tid = threadIdx.x;
    int lane = tid & 63, w = tid >> 6;
    int wm = (w & 1) * 64, wn = (w >> 1) * 64;
    f32x4 acc[4][4];
#pragma unroll
    for (int i = 0; i < 4; i++)
#pragma unroll
        for (int j = 0; j < 4; j++) acc[i][j] = (f32x4){0.f, 0.f, 0.f, 0.f};

    for (int k0 = 0; k0 < DEC_; k0 += 32) {
#pragma unroll
        for (int l = 0; l < 2; l++) {
            int idx = l * 256 + tid;         // 0..511
            int r = idx >> 2, kc = (idx & 3) * 8;
            uint4 av = *reinterpret_cast<const uint4*>(&Hbf[(size_t)(m0 + r) * DEC_ + k0 + kc]);
            *reinterpret_cast<uint4*>(&At[r][kc]) = av;
            uint4 bv = make_uint4(0u, 0u, 0u, 0u);
            if (n0 + r < V_)
                bv = *reinterpret_cast<const uint4*>(&Woutbf[(size_t)(n0 + r) * DEC_ + k0 + kc]);
            *reinterpret_cast<uint4*>(&Bt[r][kc]) = bv;
        }
        __syncthreads();
        int qk = (lane >> 4) * 8, fr = lane & 15;
        short8 a[4], bb[4];
#pragma unroll
        for (int i = 0; i < 4; i++) {
            a[i]  = *reinterpret_cast<const short8*>(&At[wm + i * 16 + fr][qk]);
            bb[i] = *reinterpret_cast<const short8*>(&Bt[wn + i * 16 + fr][qk]);
        }
#pragma unroll
        for (int i = 0; i < 4; i++)
#pragma unroll
            for (int j = 0; j < 4; j++)
                acc[i][j] = __builtin_amdgcn_mfma_f32_16x16x32_bf16(a[i], bb[j], acc[i][j], 0, 0, 0);
        __syncthreads();
    }
    int col = lane & 15, qr = (lane >> 4) * 4;
#pragma unroll
    for (int j = 0; j < 4; j++) {
        int n = n0 + wn + j * 16 + col;
        if (n < V_) {
            float bo = b_out[n];
#pragma unroll
            for (int i = 0; i < 4; i++)
#pragma unroll
                for (int r = 0; r < 4; r++) {
                    int m = m0 + wm + i * 16 + qr + r;
                    int t = m >> 6, b = m & 63;
                    out[(size_t)b * (T_ * V_) + (size_t)t * V_ + n] = acc[i][j][r] + bo;
                }
        }
    }
}

// ---------- launch ----------
extern "C" void kernel_launch(void* const* d_in, const int* in_sizes, int n_in,
                              void* d_out, int out_size, void* d_ws, size_t ws_size,
                              hipStream_t stream) {
    const float* enc       = (const float*)d_in[0];
    const int*   caption   = (const int*)d_in[1];
    const float* W_enc_att = (const float*)d_in[2];
    const float* W_dec_att = (const float*)d_in[3];
    const float* W_full    = (const float*)d_in[4];
    const float* embedding = (const float*)d_in[5];
    const float* W_init_h  = (const float*)d_in[6];
    const float* b_init_h  = (const float*)d_in[7];
    const float* W_init_c  = (const float*)d_in[8];
    const float* b_init_c  = (const float*)d_in[9];
    const float* W_ih      = (const float*)d_in[10];
    const float* b_ih      = (const float*)d_in[11];
    const float* W_hh      = (const float*)d_in[12];
    const float* b_hh      = (const float*)d_in[13];
    const float* W_out     = (const float*)d_in[14];
    const float* b_out     = (const float*)d_in[15];

    float* ws = (float*)d_ws;
    float* h0      = ws;                 // 16384
    float* c0      = ws + 16384;         // 16384
    float* WdaT    = ws + 32768;         // 65536   [256 d][256 a]
    float* WihcP   = ws + 98304;         // 524288  [512 k][256 d][4 g] packed float4
    float* WiheT   = ws + 622592;        // 262144  [256 e][1024 j]
    float* WhhP    = ws + 884736;        // 262144  [256 k][256 d][4 g] packed float4
    float* att1T   = ws + 1146880;       // 3211264 [b][a][p]
    float* embW    = ws + 4358144;       // 2883584 [t*64+b][1024]
    unsigned short* Hbf    = (unsigned short*)(ws + 7241728);  // 2816*256
    unsigned short* Woutbf = (unsigned short*)(ws + 7602176);  // 10000*256

    float* out_pred  = (float*)d_out;
    float* out_alpha = out_pred + (size_t)B_ * T_ * V_;

    k_transpose<<<dim3(8, 8),  256, 0, stream>>>(W_dec_att, WdaT, ATT_, DEC_, 0);
    k_transpose<<<dim3(8, 32), 256, 0, stream>>>(W_ih, WiheT, G4_, XW_, ENC_);
    k_packW<<<512, 256, 0, stream>>>(W_ih, WihcP, 512, 9, XW_);
    k_packW<<<256, 256, 0, stream>>>(W_hh, WhhP, 256, 8, DEC_);
    k_cvt<<<10000, 256, 0, stream>>>(W_out, Woutbf, V_ * DEC_);
    k_init_state<<<B_, 256, 0, stream>>>(enc, W_init_h, b_init_h, W_init_c, b_init_c, h0, c0);
    k_att1<<<B_ * 4, 256, 0, stream>>>(enc, W_enc_att, att1T);
    k_embW<<<176, 256, 0, stream>>>(caption, embedding, WiheT, b_ih, b_hh, embW);
    k_recur<<<B_, 1024, 0, stream>>>(enc, att1T, WdaT, W_full, WihcP, WhhP, embW,
                                     h0, c0, Hbf, out_alpha);
    k_logits<<<dim3(79, 22), 256, 0, stream>>>(Hbf, Woutbf, b_out, out_pred);
}